// Round 9
// baseline (74.876 us; speedup 1.0000x reference)
//
#include <hip/hip_runtime.h>

#define B_ 2
#define Q_ 2048
#define K_ 2048
#define H_ 16
#define D_ 64
#define HD_ (H_ * D_)
#define BQH (B_ * Q_ * H_)

// Q pre-scale: (1/sqrt(64)) * log2(e)  -> scores in log2 units; softmax uses
// raw v_exp_f32 (2^x) with no per-element multiply.
#define QSCALE 0.18033688011112042f
#define DEFER_THR 10.0f   // log2-units; P bounded by 2^10, fine in bf16/f32

typedef __bf16 bf16_t;
typedef __attribute__((ext_vector_type(8))) __bf16 bf16x8;
typedef __attribute__((ext_vector_type(4))) __bf16 bf16x4;
typedef __attribute__((ext_vector_type(4))) float f32x4;

// Raw barrier: drains LDS ops only; global register-prefetch stays in flight.
#define SBAR() do {                                         \
    __builtin_amdgcn_sched_barrier(0);                      \
    asm volatile("s_waitcnt lgkmcnt(0)" ::: "memory");      \
    __builtin_amdgcn_s_barrier();                           \
    __builtin_amdgcn_sched_barrier(0);                      \
} while (0)

// Swizzled byte offset for a [N][64] bf16 tile (row stride 128 B).
// XOR bits 4-6 with row&7: bijective, keeps 16B granules, kills bank conflicts.
__device__ __forceinline__ int swz(int row, int colByte) {
    return (row * 128 + colByte) ^ ((row & 7) << 4);
}

// SPLITK=true: block (qt, split) does half the key range, writes unnormalized
// bf16 partial O + (m,l) to workspace. SPLITK=false: round-7 direct kernel.
template<bool SPLITK>
__global__ __launch_bounds__(512, SPLITK ? 6 : 4) void attn_fwd_kernel(
    const float* __restrict__ qs, const float* __restrict__ ks,
    const float* __restrict__ vs, const int* __restrict__ valid_lens,
    float* __restrict__ out, bf16_t* __restrict__ po, float* __restrict__ ml)
{
    int qt, split;
    if constexpr (SPLITK) { qt = blockIdx.x >> 1; split = blockIdx.x & 1; }
    else                  { qt = blockIdx.x;      split = 0; }
    const int h    = blockIdx.y;
    const int b    = blockIdx.z;
    const int tid  = threadIdx.x;
    const int wave = tid >> 6;     // 0..7, each owns 16 q rows
    const int lane = tid & 63;
    const int l16  = lane & 15;
    const int lhi  = lane >> 4;    // 0..3

    const int valid  = valid_lens[b];
    const int ntiles = (valid + 63) >> 6;   // tiles fully past valid contribute exactly 0
    int tbeg = 0, tend = ntiles;
    if constexpr (SPLITK) {
        const int half = (ntiles + 1) >> 1;
        tbeg = split ? half : 0;
        tend = split ? ntiles : half;
    }

    const int qrow = qt * 128 + wave * 16 + l16;
    size_t mlslot = 0;
    if constexpr (SPLITK) {
        mlslot = ((((size_t)split * B_ + b) * Q_ + qrow) * H_ + h) * 2;
        if (tbeg >= tend) {    // empty split: weight-0 sentinel, no O write needed
            if (lhi == 0) { ml[mlslot] = -1e30f; ml[mlslot + 1] = 0.f; }
            return;
        }
    }

    __shared__ bf16_t k_lds[2][64 * 64];    // [buf][key][d], swizzled
    __shared__ bf16_t v_lds[2][64 * 64];    // [buf][d][key] transposed, swizzled
    __shared__ bf16_t p_buf[8][16 * 64];    // per-wave P tile, swizzled
    char* const pbase = (char*)&p_buf[wave][0];

    // ---- Q fragment (lane = row l16, k-dim d = dh*32+lhi*8+j), scale folded.
    const float* qp = qs + (((size_t)b * Q_ + qrow) * H_ + h) * D_;
    bf16x8 a_q[2];
    #pragma unroll
    for (int dh = 0; dh < 2; ++dh) {
        const f32x4* q4 = (const f32x4*)(qp + dh * 32 + lhi * 8);
        f32x4 lo = q4[0], hi = q4[1];
        #pragma unroll
        for (int j = 0; j < 4; ++j) {
            a_q[dh][j]     = (bf16_t)(lo[j] * QSCALE);
            a_q[dh][4 + j] = (bf16_t)(hi[j] * QSCALE);
        }
    }

    // O accumulator: C-layout of swapped PV -> lane holds q-row = l16,
    // d = t*16 + lhi*4 + r. Softmax state is per-lane scalars.
    f32x4 o_acc[4];
    #pragma unroll
    for (int t = 0; t < 4; ++t) o_acc[t] = (f32x4){0.f, 0.f, 0.f, 0.f};
    float m_r = -1e30f, l_part = 0.f;

    const float* kb = ks + ((size_t)b * K_ * H_ + h) * D_;
    const float* vg = vs + ((size_t)b * K_ * H_ + h) * D_;

    // staging role split (wave-uniform): waves 0-3 stage K, waves 4-7 stage V
    const bool kRole = (tid < 256);
    const int  st    = kRole ? tid : (tid - 256);   // 0..255
    const int  krow  = st >> 2;                     // 0..63 (key)
    const int  kcolf = (st & 3) * 16;               // float col base
    const int  vr    = (st & 15) * 4;               // key base (4 rows)
    const int  vc    = (st >> 4) * 4;               // d base (4 cols)

    f32x4 reg[4];   // in-flight next tile (lives across the barrier)

    auto issue_loads = [&](int kt) {
        if (kRole) {
            const float* ksrc = kb + (size_t)(kt * 64 + krow) * HD_ + kcolf;
            #pragma unroll
            for (int i = 0; i < 4; ++i) reg[i] = ((const f32x4*)ksrc)[i];
        } else {
            #pragma unroll
            for (int i = 0; i < 4; ++i)
                reg[i] = *(const f32x4*)(vg + (size_t)(kt * 64 + vr + i) * HD_ + vc);
        }
    };

    auto write_tile = [&](int bi) {
        if (kRole) {
            char* kdst = (char*)&k_lds[bi][0];
            bf16x8 lo, hi;
            #pragma unroll
            for (int j = 0; j < 4; ++j) {
                lo[j] = (bf16_t)reg[0][j]; lo[4 + j] = (bf16_t)reg[1][j];
                hi[j] = (bf16_t)reg[2][j]; hi[4 + j] = (bf16_t)reg[3][j];
            }
            *(bf16x8*)(kdst + swz(krow, kcolf * 2))      = lo;
            *(bf16x8*)(kdst + swz(krow, kcolf * 2 + 16)) = hi;
        } else {
            char* vdst = (char*)&v_lds[bi][0];
            #pragma unroll
            for (int j = 0; j < 4; ++j) {
                bf16x4 w;
                w[0] = (bf16_t)reg[0][j]; w[1] = (bf16_t)reg[1][j];
                w[2] = (bf16_t)reg[2][j]; w[3] = (bf16_t)reg[3][j];
                *(bf16x4*)(vdst + swz(vc + j, vr * 2)) = w;
            }
        }
    };

    // prologue: first tile straight to LDS
    issue_loads(tbeg);
    write_tile(0);
    int cur = 0;

    for (int kt = tbeg; kt < tend; ++kt) {
        const bool more = (kt + 1 < tend);
        if (more) issue_loads(kt + 1);   // stays in flight across SBAR (no vmcnt drain)
        SBAR();                          // buf[cur] ds_writes visible; readers of buf[cur^1] done

        char* const kbase = (char*)&k_lds[cur][0];
        char* const vbase = (char*)&v_lds[cur][0];

        // ---- S^T = K Q^T (swapped operands): lane holds q-row l16,
        // keys n*16 + lhi*4 + r across s[n][r].
        f32x4 s[4];
        #pragma unroll
        for (int n = 0; n < 4; ++n) s[n] = (f32x4){0.f, 0.f, 0.f, 0.f};
        __builtin_amdgcn_s_setprio(1);
        #pragma unroll
        for (int n = 0; n < 4; ++n) {
            #pragma unroll
            for (int dh = 0; dh < 2; ++dh) {
                bf16x8 ak = *(const bf16x8*)(kbase + swz(n * 16 + l16, dh * 64 + lhi * 16));
                s[n] = __builtin_amdgcn_mfma_f32_16x16x32_bf16(ak, a_q[dh], s[n], 0, 0, 0);
            }
        }
        __builtin_amdgcn_s_setprio(0);

        // ---- mask only on the boundary tile (uniform branch) ----
        if (kt * 64 + 64 > valid) {
            #pragma unroll
            for (int n = 0; n < 4; ++n) {
                const int kbase_i = kt * 64 + n * 16 + lhi * 4;
                #pragma unroll
                for (int r = 0; r < 4; ++r)
                    if (kbase_i + r >= valid) s[n][r] = -1e30f;
            }
        }

        // ---- deferred-max online softmax, all state lane-local ----
        float lm = s[0][0];
        #pragma unroll
        for (int n = 0; n < 4; ++n)
            #pragma unroll
            for (int r = 0; r < 4; ++r) lm = fmaxf(lm, s[n][r]);
        if (__any(lm > m_r + DEFER_THR)) {   // rare, wave-uniform update
            float rm = fmaxf(lm, __shfl_xor(lm, 16, 64));
            rm = fmaxf(rm, __shfl_xor(rm, 32, 64));
            const float mnew  = fmaxf(m_r, rm);
            const float alpha = __builtin_amdgcn_exp2f(m_r - mnew);
            m_r = mnew;
            l_part *= alpha;
            #pragma unroll
            for (int t = 0; t < 4; ++t) o_acc[t] *= alpha;
        }
        // P = 2^(s-m); 4 consecutive keys per n -> b64 LDS writes
        float psum = 0.f;
        #pragma unroll
        for (int n = 0; n < 4; ++n) {
            bf16x4 w;
            #pragma unroll
            for (int r = 0; r < 4; ++r) {
                const float e = __builtin_amdgcn_exp2f(s[n][r] - m_r);
                psum += e;
                w[r] = (bf16_t)e;
            }
            *(bf16x4*)(pbase + swz(l16, n * 32 + lhi * 8)) = w;
        }
        l_part += psum;

        // B-fragments of P: lane = q-col l16, k = keys kk*32 + lhi*8 + j
        bf16x8 pb[2];
        #pragma unroll
        for (int kk = 0; kk < 2; ++kk)
            pb[kk] = *(const bf16x8*)(pbase + swz(l16, kk * 64 + lhi * 16));

        // ---- PV swapped: O^T = V^T P^T -> lane = q-col, d-rows ----
        __builtin_amdgcn_s_setprio(1);
        #pragma unroll
        for (int t = 0; t < 4; ++t) {
            #pragma unroll
            for (int kk = 0; kk < 2; ++kk) {
                bf16x8 vb = *(const bf16x8*)(vbase + swz(t * 16 + l16, kk * 64 + lhi * 16));
                o_acc[t] = __builtin_amdgcn_mfma_f32_16x16x32_bf16(vb, pb[kk], o_acc[t], 0, 0, 0);
            }
        }
        __builtin_amdgcn_s_setprio(0);

        // regs -> LDS for next tile; vmcnt paid HERE (after full compute phase)
        if (more) write_tile(cur ^ 1);
        cur ^= 1;
    }

    // ---- epilogue ----
    float l = l_part;
    l += __shfl_xor(l, 16, 64);
    l += __shfl_xor(l, 32, 64);
    if constexpr (SPLITK) {
        if (lhi == 0) { ml[mlslot] = m_r; ml[mlslot + 1] = l; }
        bf16_t* pop = po + ((((size_t)split * B_ + b) * Q_ + qrow) * H_ + h) * D_;
        #pragma unroll
        for (int t = 0; t < 4; ++t) {
            bf16x4 w;
            #pragma unroll
            for (int r = 0; r < 4; ++r) w[r] = (bf16_t)o_acc[t][r];
            *(bf16x4*)(pop + t * 16 + lhi * 4) = w;
        }
    } else {
        const float inv = 1.f / l;
        float* op = out + (((size_t)b * Q_ + qrow) * H_ + h) * D_;
        #pragma unroll
        for (int t = 0; t < 4; ++t) {
            f32x4 res = o_acc[t];
            #pragma unroll
            for (int r = 0; r < 4; ++r) res[r] *= inv;
            *(f32x4*)(op + t * 16 + lhi * 4) = res;
        }
    }
}

// Merge the two splits: out = (2^(m0-M) O0 + 2^(m1-M) O1) / (2^(m0-M) l0 + 2^(m1-M) l1).
__global__ __launch_bounds__(256) void attn_combine(
    const bf16_t* __restrict__ po, const float* __restrict__ ml,
    float* __restrict__ out)
{
    const int idx  = blockIdx.x * 256 + threadIdx.x;   // < BQH*16
    const int dv   = idx & 15;                         // which f32x4 within D
    const int slot = idx >> 4;                         // (b*Q+q)*H+h
    const float2 ml0 = ((const float2*)ml)[slot];
    const float2 ml1 = ((const float2*)ml)[BQH + slot];
    const float M   = fmaxf(ml0.x, ml1.x);
    const float c0  = exp2f(ml0.x - M);
    const float c1  = exp2f(ml1.x - M);   // 0 exactly when split empty (m=-1e30)
    const float inv = 1.f / (c0 * ml0.y + c1 * ml1.y);
    bf16x4 p0 = *(const bf16x4*)(po + (size_t)slot * D_ + dv * 4);
    bf16x4 p1 = *(const bf16x4*)(po + (size_t)BQH * D_ + (size_t)slot * D_ + dv * 4);
    f32x4 o;
    #pragma unroll
    for (int r = 0; r < 4; ++r)
        o[r] = (c0 * (float)p0[r] + c1 * (float)p1[r]) * inv;
    *(f32x4*)(out + (size_t)slot * D_ + dv * 4) = o;
}

extern "C" void kernel_launch(void* const* d_in, const int* in_sizes, int n_in,
                              void* d_out, int out_size, void* d_ws, size_t ws_size,
                              hipStream_t stream) {
    const float* qs = (const float*)d_in[0];
    const float* ks = (const float*)d_in[1];
    const float* vs = (const float*)d_in[2];
    const int*   vl = (const int*)d_in[3];
    float*       out = (float*)d_out;

    const size_t po_bytes = (size_t)2 * BQH * D_ * sizeof(bf16_t);   // 16.78 MB
    const size_t ml_bytes = (size_t)2 * BQH * 2 * sizeof(float);     //  2.10 MB
    if (ws_size >= po_bytes + ml_bytes) {
        bf16_t* po = (bf16_t*)d_ws;
        float*  ml = (float*)((char*)d_ws + po_bytes);
        attn_fwd_kernel<true><<<dim3(32, 16, 2), 512, 0, stream>>>(qs, ks, vs, vl, nullptr, po, ml);
        attn_combine<<<dim3((BQH * 16) / 256), 256, 0, stream>>>(po, ml, out);
    } else {
        attn_fwd_kernel<false><<<dim3(16, 16, 2), 512, 0, stream>>>(qs, ks, vs, vl, out, nullptr, nullptr);
    }
}

// Round 10
// 47.202 us; speedup vs baseline: 1.5863x; 1.5863x over previous
//
#include <hip/hip_runtime.h>

#define B_ 2
#define Q_ 2048
#define K_ 2048
#define H_ 16
#define D_ 64
#define HD_ (H_ * D_)
#define BQH (B_ * Q_ * H_)

// Q pre-scale: (1/sqrt(64)) * log2(e)  -> scores in log2 units; softmax uses
// raw v_exp_f32 (2^x) with no per-element multiply.
#define QSCALE 0.18033688011112042f
#define DEFER_THR 10.0f   // log2-units; P bounded by 2^10, fine in bf16/f32

typedef __bf16 bf16_t;
typedef __attribute__((ext_vector_type(8))) __bf16 bf16x8;
typedef __attribute__((ext_vector_type(4))) __bf16 bf16x4;
typedef __attribute__((ext_vector_type(4))) float f32x4;

// Raw barrier: drains LDS ops only; global register-prefetch stays in flight.
#define SBAR() do {                                         \
    __builtin_amdgcn_sched_barrier(0);                      \
    asm volatile("s_waitcnt lgkmcnt(0)" ::: "memory");      \
    __builtin_amdgcn_s_barrier();                           \
    __builtin_amdgcn_sched_barrier(0);                      \
} while (0)

// Swizzled byte offset for a [N][64] bf16 tile (row stride 128 B).
// XOR bits 4-6 with row&7: bijective, keeps 16B granules, kills bank conflicts.
__device__ __forceinline__ int swz(int row, int colByte) {
    return (row * 128 + colByte) ^ ((row & 7) << 4);
}

// SPLITK=true: block (qt, split) does half the key range, writes unnormalized
// bf16 partial O + (m,l) to workspace. SPLITK=false: round-7 direct kernel.
// NOTE: min-waves stays 4 (VGPR cap 128) — forcing 6 capped VGPR at 85 and
// spilled ~126 B/thread to scratch (r9: VGPR 40, WRITE_SIZE +66 MB, 2x slower).
template<bool SPLITK>
__global__ __launch_bounds__(512, 4) void attn_fwd_kernel(
    const float* __restrict__ qs, const float* __restrict__ ks,
    const float* __restrict__ vs, const int* __restrict__ valid_lens,
    float* __restrict__ out, bf16_t* __restrict__ po, float* __restrict__ ml)
{
    int qt, split;
    if constexpr (SPLITK) { qt = blockIdx.x >> 1; split = blockIdx.x & 1; }
    else                  { qt = blockIdx.x;      split = 0; }
    const int h    = blockIdx.y;
    const int b    = blockIdx.z;
    const int tid  = threadIdx.x;
    const int wave = tid >> 6;     // 0..7, each owns 16 q rows
    const int lane = tid & 63;
    const int l16  = lane & 15;
    const int lhi  = lane >> 4;    // 0..3

    const int valid  = valid_lens[b];
    const int ntiles = (valid + 63) >> 6;   // tiles fully past valid contribute exactly 0
    int tbeg = 0, tend = ntiles;
    if constexpr (SPLITK) {
        const int half = (ntiles + 1) >> 1;
        tbeg = split ? half : 0;
        tend = split ? ntiles : half;
    }

    const int qrow = qt * 128 + wave * 16 + l16;
    size_t mlslot = 0;
    if constexpr (SPLITK) {
        mlslot = ((((size_t)split * B_ + b) * Q_ + qrow) * H_ + h) * 2;
        if (tbeg >= tend) {    // empty split: weight-0 sentinel, no O write needed
            if (lhi == 0) { ml[mlslot] = -1e30f; ml[mlslot + 1] = 0.f; }
            return;
        }
    }

    __shared__ bf16_t k_lds[2][64 * 64];    // [buf][key][d], swizzled
    __shared__ bf16_t v_lds[2][64 * 64];    // [buf][d][key] transposed, swizzled
    __shared__ bf16_t p_buf[8][16 * 64];    // per-wave P tile, swizzled
    char* const pbase = (char*)&p_buf[wave][0];

    // ---- Q fragment (lane = row l16, k-dim d = dh*32+lhi*8+j), scale folded.
    const float* qp = qs + (((size_t)b * Q_ + qrow) * H_ + h) * D_;
    bf16x8 a_q[2];
    #pragma unroll
    for (int dh = 0; dh < 2; ++dh) {
        const f32x4* q4 = (const f32x4*)(qp + dh * 32 + lhi * 8);
        f32x4 lo = q4[0], hi = q4[1];
        #pragma unroll
        for (int j = 0; j < 4; ++j) {
            a_q[dh][j]     = (bf16_t)(lo[j] * QSCALE);
            a_q[dh][4 + j] = (bf16_t)(hi[j] * QSCALE);
        }
    }

    // O accumulator: C-layout of swapped PV -> lane holds q-row = l16,
    // d = t*16 + lhi*4 + r. Softmax state is per-lane scalars.
    f32x4 o_acc[4];
    #pragma unroll
    for (int t = 0; t < 4; ++t) o_acc[t] = (f32x4){0.f, 0.f, 0.f, 0.f};
    float m_r = -1e30f, l_part = 0.f;

    const float* kb = ks + ((size_t)b * K_ * H_ + h) * D_;
    const float* vg = vs + ((size_t)b * K_ * H_ + h) * D_;

    // staging role split (wave-uniform): waves 0-3 stage K, waves 4-7 stage V
    const bool kRole = (tid < 256);
    const int  st    = kRole ? tid : (tid - 256);   // 0..255
    const int  krow  = st >> 2;                     // 0..63 (key)
    const int  kcolf = (st & 3) * 16;               // float col base
    const int  vr    = (st & 15) * 4;               // key base (4 rows)
    const int  vc    = (st >> 4) * 4;               // d base (4 cols)

    f32x4 reg[4];   // in-flight next tile (lives across the barrier)

    auto issue_loads = [&](int kt) {
        if (kRole) {
            const float* ksrc = kb + (size_t)(kt * 64 + krow) * HD_ + kcolf;
            #pragma unroll
            for (int i = 0; i < 4; ++i) reg[i] = ((const f32x4*)ksrc)[i];
        } else {
            #pragma unroll
            for (int i = 0; i < 4; ++i)
                reg[i] = *(const f32x4*)(vg + (size_t)(kt * 64 + vr + i) * HD_ + vc);
        }
    };

    auto write_tile = [&](int bi) {
        if (kRole) {
            char* kdst = (char*)&k_lds[bi][0];
            bf16x8 lo, hi;
            #pragma unroll
            for (int j = 0; j < 4; ++j) {
                lo[j] = (bf16_t)reg[0][j]; lo[4 + j] = (bf16_t)reg[1][j];
                hi[j] = (bf16_t)reg[2][j]; hi[4 + j] = (bf16_t)reg[3][j];
            }
            *(bf16x8*)(kdst + swz(krow, kcolf * 2))      = lo;
            *(bf16x8*)(kdst + swz(krow, kcolf * 2 + 16)) = hi;
        } else {
            char* vdst = (char*)&v_lds[bi][0];
            #pragma unroll
            for (int j = 0; j < 4; ++j) {
                bf16x4 w;
                w[0] = (bf16_t)reg[0][j]; w[1] = (bf16_t)reg[1][j];
                w[2] = (bf16_t)reg[2][j]; w[3] = (bf16_t)reg[3][j];
                *(bf16x4*)(vdst + swz(vc + j, vr * 2)) = w;
            }
        }
    };

    // prologue: first tile straight to LDS
    issue_loads(tbeg);
    write_tile(0);
    int cur = 0;

    for (int kt = tbeg; kt < tend; ++kt) {
        const bool more = (kt + 1 < tend);
        if (more) issue_loads(kt + 1);   // stays in flight across SBAR (no vmcnt drain)
        SBAR();                          // buf[cur] ds_writes visible; readers of buf[cur^1] done

        char* const kbase = (char*)&k_lds[cur][0];
        char* const vbase = (char*)&v_lds[cur][0];

        // ---- S^T = K Q^T (swapped operands): lane holds q-row l16,
        // keys n*16 + lhi*4 + r across s[n][r].
        f32x4 s[4];
        #pragma unroll
        for (int n = 0; n < 4; ++n) s[n] = (f32x4){0.f, 0.f, 0.f, 0.f};
        __builtin_amdgcn_s_setprio(1);
        #pragma unroll
        for (int n = 0; n < 4; ++n) {
            #pragma unroll
            for (int dh = 0; dh < 2; ++dh) {
                bf16x8 ak = *(const bf16x8*)(kbase + swz(n * 16 + l16, dh * 64 + lhi * 16));
                s[n] = __builtin_amdgcn_mfma_f32_16x16x32_bf16(ak, a_q[dh], s[n], 0, 0, 0);
            }
        }
        __builtin_amdgcn_s_setprio(0);

        // ---- mask only on the boundary tile (uniform branch) ----
        if (kt * 64 + 64 > valid) {
            #pragma unroll
            for (int n = 0; n < 4; ++n) {
                const int kbase_i = kt * 64 + n * 16 + lhi * 4;
                #pragma unroll
                for (int r = 0; r < 4; ++r)
                    if (kbase_i + r >= valid) s[n][r] = -1e30f;
            }
        }

        // ---- deferred-max online softmax, all state lane-local ----
        float lm = s[0][0];
        #pragma unroll
        for (int n = 0; n < 4; ++n)
            #pragma unroll
            for (int r = 0; r < 4; ++r) lm = fmaxf(lm, s[n][r]);
        if (__any(lm > m_r + DEFER_THR)) {   // rare, wave-uniform update
            float rm = fmaxf(lm, __shfl_xor(lm, 16, 64));
            rm = fmaxf(rm, __shfl_xor(rm, 32, 64));
            const float mnew  = fmaxf(m_r, rm);
            const float alpha = __builtin_amdgcn_exp2f(m_r - mnew);
            m_r = mnew;
            l_part *= alpha;
            #pragma unroll
            for (int t = 0; t < 4; ++t) o_acc[t] *= alpha;
        }
        // P = 2^(s-m); 4 consecutive keys per n -> b64 LDS writes
        float psum = 0.f;
        #pragma unroll
        for (int n = 0; n < 4; ++n) {
            bf16x4 w;
            #pragma unroll
            for (int r = 0; r < 4; ++r) {
                const float e = __builtin_amdgcn_exp2f(s[n][r] - m_r);
                psum += e;
                w[r] = (bf16_t)e;
            }
            *(bf16x4*)(pbase + swz(l16, n * 32 + lhi * 8)) = w;
        }
        l_part += psum;

        // B-fragments of P: lane = q-col l16, k = keys kk*32 + lhi*8 + j
        bf16x8 pb[2];
        #pragma unroll
        for (int kk = 0; kk < 2; ++kk)
            pb[kk] = *(const bf16x8*)(pbase + swz(l16, kk * 64 + lhi * 16));

        // ---- PV swapped: O^T = V^T P^T -> lane = q-col, d-rows ----
        __builtin_amdgcn_s_setprio(1);
        #pragma unroll
        for (int t = 0; t < 4; ++t) {
            #pragma unroll
            for (int kk = 0; kk < 2; ++kk) {
                bf16x8 vb = *(const bf16x8*)(vbase + swz(t * 16 + l16, kk * 64 + lhi * 16));
                o_acc[t] = __builtin_amdgcn_mfma_f32_16x16x32_bf16(vb, pb[kk], o_acc[t], 0, 0, 0);
            }
        }
        __builtin_amdgcn_s_setprio(0);

        // regs -> LDS for next tile; vmcnt paid HERE (after full compute phase)
        if (more) write_tile(cur ^ 1);
        cur ^= 1;
    }

    // ---- epilogue ----
    float l = l_part;
    l += __shfl_xor(l, 16, 64);
    l += __shfl_xor(l, 32, 64);
    if constexpr (SPLITK) {
        if (lhi == 0) { ml[mlslot] = m_r; ml[mlslot + 1] = l; }
        bf16_t* pop = po + ((((size_t)split * B_ + b) * Q_ + qrow) * H_ + h) * D_;
        #pragma unroll
        for (int t = 0; t < 4; ++t) {
            bf16x4 w;
            #pragma unroll
            for (int r = 0; r < 4; ++r) w[r] = (bf16_t)o_acc[t][r];
            *(bf16x4*)(pop + t * 16 + lhi * 4) = w;
        }
    } else {
        const float inv = 1.f / l;
        float* op = out + (((size_t)b * Q_ + qrow) * H_ + h) * D_;
        #pragma unroll
        for (int t = 0; t < 4; ++t) {
            f32x4 res = o_acc[t];
            #pragma unroll
            for (int r = 0; r < 4; ++r) res[r] *= inv;
            *(f32x4*)(op + t * 16 + lhi * 4) = res;
        }
    }
}

// Merge the two splits: out = (2^(m0-M) O0 + 2^(m1-M) O1) / (2^(m0-M) l0 + 2^(m1-M) l1).
__global__ __launch_bounds__(256) void attn_combine(
    const bf16_t* __restrict__ po, const float* __restrict__ ml,
    float* __restrict__ out)
{
    const int idx  = blockIdx.x * 256 + threadIdx.x;   // < BQH*16
    const int dv   = idx & 15;                         // which f32x4 within D
    const int slot = idx >> 4;                         // (b*Q+q)*H+h
    const float2 ml0 = ((const float2*)ml)[slot];
    const float2 ml1 = ((const float2*)ml)[BQH + slot];
    const float M   = fmaxf(ml0.x, ml1.x);
    const float c0  = exp2f(ml0.x - M);
    const float c1  = exp2f(ml1.x - M);   // 0 exactly when split empty (m=-1e30)
    const float inv = 1.f / (c0 * ml0.y + c1 * ml1.y);
    bf16x4 p0 = *(const bf16x4*)(po + (size_t)slot * D_ + dv * 4);
    bf16x4 p1 = *(const bf16x4*)(po + (size_t)BQH * D_ + (size_t)slot * D_ + dv * 4);
    f32x4 o;
    #pragma unroll
    for (int r = 0; r < 4; ++r)
        o[r] = (c0 * (float)p0[r] + c1 * (float)p1[r]) * inv;
    *(f32x4*)(out + (size_t)slot * D_ + dv * 4) = o;
}

extern "C" void kernel_launch(void* const* d_in, const int* in_sizes, int n_in,
                              void* d_out, int out_size, void* d_ws, size_t ws_size,
                              hipStream_t stream) {
    const float* qs = (const float*)d_in[0];
    const float* ks = (const float*)d_in[1];
    const float* vs = (const float*)d_in[2];
    const int*   vl = (const int*)d_in[3];
    float*       out = (float*)d_out;

    const size_t po_bytes = (size_t)2 * BQH * D_ * sizeof(bf16_t);   // 16.78 MB
    const size_t ml_bytes = (size_t)2 * BQH * 2 * sizeof(float);     //  2.10 MB
    if (ws_size >= po_bytes + ml_bytes) {
        bf16_t* po = (bf16_t*)d_ws;
        float*  ml = (float*)((char*)d_ws + po_bytes);
        attn_fwd_kernel<true><<<dim3(32, 16, 2), 512, 0, stream>>>(qs, ks, vs, vl, nullptr, po, ml);
        attn_combine<<<dim3((BQH * 16) / 256), 256, 0, stream>>>(po, ml, out);
    } else {
        attn_fwd_kernel<false><<<dim3(16, 16, 2), 512, 0, stream>>>(qs, ks, vs, vl, out, nullptr, nullptr);
    }
}